// Round 8
// baseline (579.482 us; speedup 1.0000x reference)
//
#include <hip/hip_runtime.h>

#define B_DIM 1024
#define T_DIM 512
#define D_IN 32
#define H 64
#define CT 32                 // timesteps per staged X chunk
#define NCHUNK (T_DIM / CT)   // 16
#define KB 2                  // batches per wave

// ---------------------------------------------------------------------------
// One wave per KB=2 batch elements; lane i owns hidden unit i of BOTH.
// Weights (whh row, wc row) are shared across the two batches -> the second
// batch adds an independent dependency chain that fills the first one's
// stall windows (R3/R5: ~988 cyc/step invariant across issue counts =>
// stall-bound, not issue-bound).
// h exchange via LDS broadcast (write h_i -> 16x ds_read_b128, same-address
// broadcast = conflict-free). x-projection FMAs are independent of h and
// sit in front of the h-FMAs to cover the LDS write->read round trip.
// ---------------------------------------------------------------------------
__global__ __attribute__((amdgpu_flat_work_group_size(64, 64),
                          amdgpu_waves_per_eu(1, 1)))
void rnn_kernel(
    const float* __restrict__ X,      // [B][T][D_IN]
    const float* __restrict__ W_emb,  // [H][D_IN]
    const float* __restrict__ b_emb,  // [H]
    const float* __restrict__ W_ih,   // [H][H]
    const float* __restrict__ b_ih,   // [H]
    const float* __restrict__ W_hh,   // [H][H]
    const float* __restrict__ b_hh,   // [H]
    const float* __restrict__ W_out,  // [1][H]
    const float* __restrict__ b_out,  // [1]
    float* __restrict__ out)          // [B]
{
    __shared__ __align__(16) float wemb[H * D_IN];      // 8 KB (prologue only)
    __shared__ __align__(16) float bemb[H];
    __shared__ __align__(16) float xsA[2][CT * D_IN];   // 8 KB batch A
    __shared__ __align__(16) float xsB[2][CT * D_IN];   // 8 KB batch B
    __shared__ __align__(16) float hsA[H];
    __shared__ __align__(16) float hsB[H];

    const int i  = threadIdx.x;       // lane 0..63
    const int b0 = blockIdx.x * KB;

    const float* __restrict__ xbA = X + (size_t)b0 * T_DIM * D_IN;
    const float* __restrict__ xbB = X + (size_t)(b0 + 1) * T_DIM * D_IN;

    // ---- kick off chunk-0 global loads early ----
    float4 sA0 = *(const float4*)&xbA[0 * 256 + i * 4];
    float4 sA1 = *(const float4*)&xbA[1 * 256 + i * 4];
    float4 sA2 = *(const float4*)&xbA[2 * 256 + i * 4];
    float4 sA3 = *(const float4*)&xbA[3 * 256 + i * 4];
    float4 sB0 = *(const float4*)&xbB[0 * 256 + i * 4];
    float4 sB1 = *(const float4*)&xbB[1 * 256 + i * 4];
    float4 sB2 = *(const float4*)&xbB[2 * 256 + i * 4];
    float4 sB3 = *(const float4*)&xbB[3 * 256 + i * 4];

    // ---- stage W_emb + b_emb into LDS (coalesced) ----
    #pragma unroll
    for (int k = 0; k < 8; ++k)
        *(float4*)&wemb[k * 256 + i * 4] = *(const float4*)&W_emb[k * 256 + i * 4];
    bemb[i] = b_emb[i];

    // ---- W_ih row i -> registers ----
    float wih[H];
    #pragma unroll
    for (int j = 0; j < H; j += 4) {
        const float4 v = *(const float4*)&W_ih[i * H + j];
        wih[j] = v.x; wih[j + 1] = v.y; wih[j + 2] = v.z; wih[j + 3] = v.w;
    }

    // ---- fold: wc = row i of W_ih@W_emb ; ci = b_ih+b_hh+W_ih@b_emb ----
    float wc[D_IN];
    #pragma unroll
    for (int d = 0; d < D_IN; ++d) wc[d] = 0.f;
    float ci = b_ih[i] + b_hh[i];
    #pragma unroll 4
    for (int j = 0; j < H; ++j) {
        const float wj = wih[j];
        ci += wj * bemb[j];
        #pragma unroll
        for (int d = 0; d < D_IN; d += 4) {
            const float4 e = *(const float4*)&wemb[j * D_IN + d];
            wc[d]     += wj * e.x;
            wc[d + 1] += wj * e.y;
            wc[d + 2] += wj * e.z;
            wc[d + 3] += wj * e.w;
        }
    }

    // ---- W_hh row i -> registers ----
    float whh[H];
    #pragma unroll
    for (int j = 0; j < H; j += 4) {
        const float4 v = *(const float4*)&W_hh[i * H + j];
        whh[j] = v.x; whh[j + 1] = v.y; whh[j + 2] = v.z; whh[j + 3] = v.w;
    }

    // Pin loop invariants into VGPRs (R3: proved necessary for residency).
    #pragma unroll
    for (int j = 0; j < H; ++j) asm volatile("" : "+v"(whh[j]));
    #pragma unroll
    for (int d = 0; d < D_IN; ++d) asm volatile("" : "+v"(wc[d]));
    asm volatile("" : "+v"(ci));

    // ---- write chunk 0 + zero h ----
    *(float4*)&xsA[0][0 * 256 + i * 4] = sA0;
    *(float4*)&xsA[0][1 * 256 + i * 4] = sA1;
    *(float4*)&xsA[0][2 * 256 + i * 4] = sA2;
    *(float4*)&xsA[0][3 * 256 + i * 4] = sA3;
    *(float4*)&xsB[0][0 * 256 + i * 4] = sB0;
    *(float4*)&xsB[0][1 * 256 + i * 4] = sB1;
    *(float4*)&xsB[0][2 * 256 + i * 4] = sB2;
    *(float4*)&xsB[0][3 * 256 + i * 4] = sB3;
    hsA[i] = 0.f;
    hsB[i] = 0.f;

    float hA = 0.f, hB = 0.f;

    #pragma unroll 1
    for (int c = 0; c < NCHUNK; ++c) {
        const int cur = c & 1;
        float4 pA0, pA1, pA2, pA3, pB0, pB1, pB2, pB3;
        if (c + 1 < NCHUNK) {
            const float* __restrict__ nA = &xbA[(c + 1) * (CT * D_IN)];
            const float* __restrict__ nB = &xbB[(c + 1) * (CT * D_IN)];
            pA0 = *(const float4*)&nA[0 * 256 + i * 4];
            pA1 = *(const float4*)&nA[1 * 256 + i * 4];
            pA2 = *(const float4*)&nA[2 * 256 + i * 4];
            pA3 = *(const float4*)&nA[3 * 256 + i * 4];
            pB0 = *(const float4*)&nB[0 * 256 + i * 4];
            pB1 = *(const float4*)&nB[1 * 256 + i * 4];
            pB2 = *(const float4*)&nB[2 * 256 + i * 4];
            pB3 = *(const float4*)&nB[3 * 256 + i * 4];
        }

        #pragma unroll 2
        for (int tt = 0; tt < CT; ++tt) {
            const float* __restrict__ xrA = &xsA[cur][tt * D_IN];
            const float* __restrict__ xrB = &xsB[cur][tt * D_IN];

            float aA0 = ci, aA1 = 0.f, aA2 = 0.f, aA3 = 0.f;
            float aB0 = ci, aB1 = 0.f, aB2 = 0.f, aB3 = 0.f;

            // x-projection (independent of h -> covers the h LDS round trip)
            #pragma unroll
            for (int d = 0; d < D_IN; d += 8) {
                const float4 xa0 = *(const float4*)&xrA[d];
                const float4 xa1 = *(const float4*)&xrA[d + 4];
                const float4 xb0 = *(const float4*)&xrB[d];
                const float4 xb1 = *(const float4*)&xrB[d + 4];
                aA0 += wc[d]     * xa0.x;  aA1 += wc[d + 1] * xa0.y;
                aA2 += wc[d + 2] * xa0.z;  aA3 += wc[d + 3] * xa0.w;
                aB0 += wc[d]     * xb0.x;  aB1 += wc[d + 1] * xb0.y;
                aB2 += wc[d + 2] * xb0.z;  aB3 += wc[d + 3] * xb0.w;
                aA0 += wc[d + 4] * xa1.x;  aA1 += wc[d + 5] * xa1.y;
                aA2 += wc[d + 6] * xa1.z;  aA3 += wc[d + 7] * xa1.w;
                aB0 += wc[d + 4] * xb1.x;  aB1 += wc[d + 5] * xb1.y;
                aB2 += wc[d + 6] * xb1.z;  aB3 += wc[d + 7] * xb1.w;
            }

            // recurrent matvec: broadcast reads of h, two interleaved chains
            #pragma unroll
            for (int j = 0; j < H; j += 8) {
                const float4 ha0 = *(const float4*)&hsA[j];
                const float4 ha1 = *(const float4*)&hsA[j + 4];
                const float4 hb0 = *(const float4*)&hsB[j];
                const float4 hb1 = *(const float4*)&hsB[j + 4];
                aA0 += whh[j]     * ha0.x;  aA1 += whh[j + 1] * ha0.y;
                aA2 += whh[j + 2] * ha0.z;  aA3 += whh[j + 3] * ha0.w;
                aB0 += whh[j]     * hb0.x;  aB1 += whh[j + 1] * hb0.y;
                aB2 += whh[j + 2] * hb0.z;  aB3 += whh[j + 3] * hb0.w;
                aA0 += whh[j + 4] * ha1.x;  aA1 += whh[j + 5] * ha1.y;
                aA2 += whh[j + 6] * ha1.z;  aA3 += whh[j + 7] * ha1.w;
                aB0 += whh[j + 4] * hb1.x;  aB1 += whh[j + 5] * hb1.y;
                aB2 += whh[j + 6] * hb1.z;  aB3 += whh[j + 7] * hb1.w;
            }

            const float accA = (aA0 + aA1) + (aA2 + aA3);
            const float accB = (aB0 + aB1) + (aB2 + aB3);
            // tanh(x) = 1 - 2/(exp(2x)+1)
            const float eA = __builtin_amdgcn_exp2f(accA * 2.885390081777927f);
            const float eB = __builtin_amdgcn_exp2f(accB * 2.885390081777927f);
            hA = __builtin_fmaf(-2.f, __builtin_amdgcn_rcpf(eA + 1.f), 1.f);
            hB = __builtin_fmaf(-2.f, __builtin_amdgcn_rcpf(eB + 1.f), 1.f);
            hsA[i] = hA;              // single wave: DS pipe is in-order
            hsB[i] = hB;
        }

        if (c + 1 < NCHUNK) {
            const int nxt = cur ^ 1;
            *(float4*)&xsA[nxt][0 * 256 + i * 4] = pA0;
            *(float4*)&xsA[nxt][1 * 256 + i * 4] = pA1;
            *(float4*)&xsA[nxt][2 * 256 + i * 4] = pA2;
            *(float4*)&xsA[nxt][3 * 256 + i * 4] = pA3;
            *(float4*)&xsB[nxt][0 * 256 + i * 4] = pB0;
            *(float4*)&xsB[nxt][1 * 256 + i * 4] = pB1;
            *(float4*)&xsB[nxt][2 * 256 + i * 4] = pB2;
            *(float4*)&xsB[nxt][3 * 256 + i * 4] = pB3;
        }
    }

    // ---- output projection for both batches ----
    const float wo = W_out[i];
    float vA = hA * wo;
    float vB = hB * wo;
    #pragma unroll
    for (int off = 32; off > 0; off >>= 1) {
        vA += __shfl_xor(vA, off, 64);
        vB += __shfl_xor(vB, off, 64);
    }
    if (i == 0) {
        const float bo = b_out[0];
        out[b0]     = vA + bo;
        out[b0 + 1] = vB + bo;
    }
}

// ---------------------------------------------------------------------------
extern "C" void kernel_launch(void* const* d_in, const int* in_sizes, int n_in,
                              void* d_out, int out_size, void* d_ws, size_t ws_size,
                              hipStream_t stream) {
    const float* X     = (const float*)d_in[0];
    const float* W_emb = (const float*)d_in[1];
    const float* b_emb = (const float*)d_in[2];
    const float* W_ih  = (const float*)d_in[3];
    const float* b_ih  = (const float*)d_in[4];
    const float* W_hh  = (const float*)d_in[5];
    const float* b_hh  = (const float*)d_in[6];
    const float* W_out = (const float*)d_in[7];
    const float* b_out = (const float*)d_in[8];
    float* out = (float*)d_out;

    rnn_kernel<<<B_DIM / KB, 64, 0, stream>>>(X, W_emb, b_emb, W_ih, b_ih,
                                              W_hh, b_hh, W_out, b_out, out);
}